// Round 1
// baseline (110.619 us; speedup 1.0000x reference)
//
#include <hip/hip_runtime.h>

__global__ __launch_bounds__(256) void bingham_kl_kernel(
    const float* __restrict__ q1, const float* __restrict__ z1,
    const float* __restrict__ q2, const float* __restrict__ z2,
    const float* __restrict__ F1, const float* __restrict__ dF1,
    const float* __restrict__ F2, float* __restrict__ out, int n)
{
    int i = blockIdx.x * blockDim.x + threadIdx.x;
    if (i >= n) return;

    const float4 Q1 = reinterpret_cast<const float4*>(q1)[i];
    const float4 Q2 = reinterpret_cast<const float4*>(q2)[i];
    const float a1 = Q1.x, b1 = Q1.y, c1 = Q1.z, d1 = Q1.w;
    const float a2 = Q2.x, b2 = Q2.y, c2 = Q2.z, d2 = Q2.w;

    // V2 rows (quat basis of q2)
    const float w[3][4] = {
        {  d2,  c2, -b2, -a2 },
        { -c2,  d2,  a2, -b2 },
        { -b2,  a2, -d2,  c2 }
    };
    // Columns of V1_ft = [q1 | V1^T]; V1_ft is orthogonal -> inv = transpose.
    // Column j of V1_ft dotted with V2 row i gives the pre-square A entry.
    const float col[4][4] = {
        {  a1,  b1,  c1,  d1 },   // col 0 = q1
        {  d1,  c1, -b1, -a1 },   // col 1 = V1 row 0
        { -c1,  d1,  a1, -b1 },   // col 2 = V1 row 1
        { -b1,  a1, -d1,  c1 }    // col 3 = V1 row 2
    };

    const float z10 = z1[3*i+0], z11 = z1[3*i+1], z12 = z1[3*i+2];
    const float z20 = z2[3*i+0], z21 = z2[3*i+1], z22 = z2[3*i+2];
    const float g0  = dF1[3*i+0], g1 = dF1[3*i+1], g2 = dF1[3*i+2];
    const float f1 = F1[i];
    const float f2 = F2[i];

    const float inv_f1 = 1.0f / f1;
    const float r0 = g0 * inv_f1, r1 = g1 * inv_f1, r2 = g2 * inv_f1;
    const float s = 1.0f - (r0 + r1 + r2);

    float H[3];
    #pragma unroll
    for (int ii = 0; ii < 3; ++ii) {
        float A0 = w[ii][0]*col[0][0] + w[ii][1]*col[0][1] + w[ii][2]*col[0][2] + w[ii][3]*col[0][3];
        float A1 = w[ii][0]*col[1][0] + w[ii][1]*col[1][1] + w[ii][2]*col[1][2] + w[ii][3]*col[1][3];
        float A2 = w[ii][0]*col[2][0] + w[ii][1]*col[2][1] + w[ii][2]*col[2][2] + w[ii][3]*col[2][3];
        float A3 = w[ii][0]*col[3][0] + w[ii][1]*col[3][1] + w[ii][2]*col[3][2] + w[ii][3]*col[3][3];
        H[ii] = A0*A0*s + A1*A1*r0 + A2*A2*r1 + A3*A3*r2;
    }

    // Z2 = reverse(z2): sum = z2[2]*H[0] + z2[1]*H[1] + z2[0]*H[2]
    const float cross = __logf(f2) - (z22*H[0] + z21*H[1] + z20*H[2]);
    // Z1 = reverse(z1): sum(Z1*dF1) = z1[2]*g0 + z1[1]*g1 + z1[0]*g2
    const float ent1  = __logf(f1) - (z12*g0 + z11*g1 + z10*g2) * inv_f1;

    out[i] = cross - ent1;
}

extern "C" void kernel_launch(void* const* d_in, const int* in_sizes, int n_in,
                              void* d_out, int out_size, void* d_ws, size_t ws_size,
                              hipStream_t stream) {
    const float* q1  = (const float*)d_in[0];
    const float* z1  = (const float*)d_in[1];
    const float* q2  = (const float*)d_in[2];
    const float* z2  = (const float*)d_in[3];
    const float* F1  = (const float*)d_in[4];
    const float* dF1 = (const float*)d_in[5];
    const float* F2  = (const float*)d_in[6];
    float* out = (float*)d_out;

    const int n = out_size;  // B rows
    const int block = 256;
    const int grid = (n + block - 1) / block;
    bingham_kl_kernel<<<grid, block, 0, stream>>>(q1, z1, q2, z2, F1, dF1, F2, out, n);
}